// Round 1
// 1341.892 us; speedup vs baseline: 1.0038x; 1.0038x over previous
//
#include <hip/hip_runtime.h>

// Problem constants (from reference):
//   G = 500000 groups, N = 2000000 items, D = 128 feature dim, F = 8 map cols, FEAT = 0.
// Outputs (concatenated flat, fp32): x_pool (G*D) then x_seen (G) as 0.0/1.0.
//
// Single fused kernel:
//   Phase A: one thread per group, sequential CSR scan with strict '>' -> exact
//            reference semantics (segment_max then min-index-among-ties), bitwise
//            identical fp32 compares, no arithmetic. Empty group -> arg=n_items.
//            args parked in LDS (no global scratch round-trip).
//   Phase B: 32 lanes per group row (32 x float4 = 512 B), 8 warps/block iterate
//            over the block's 256 groups. Gather indices are monotone through
//            x_mod -> near-sequential HBM reads. Non-temporal on the single-use
//            streaming traffic (x_mod rows, x_pool writes) so L2 keeps x_map/csr.

#define D_DIM 128
#define F_COLS 8
#define GROUPS_PER_BLOCK 256
#define BLOCK_THREADS 256

typedef float f4 __attribute__((ext_vector_type(4)));

__global__ __launch_bounds__(BLOCK_THREADS) void fused_csr_pool_kernel(
    const float* __restrict__ x_mod,
    const float* __restrict__ x_map,
    const int*   __restrict__ csr_idx,
    float* __restrict__ x_pool,
    float* __restrict__ x_seen,
    int n_groups, int n_items)
{
    __shared__ int s_arg[GROUPS_PER_BLOCK];

    const int g0 = blockIdx.x * GROUPS_PER_BLOCK;
    const int g  = g0 + threadIdx.x;

    // ---- Phase A: per-group argmax over x_map[:, FEAT=0] ----
    if (g < n_groups) {
        const int start = csr_idx[g];
        const int end   = csr_idx[g + 1];
        float best = -INFINITY;
        int   arg  = n_items;                    // sentinel: empty group -> zeros row
        for (int i = start; i < end; ++i) {
            float v = x_map[(size_t)i * F_COLS]; // column 0, stride F
            if (v > best) { best = v; arg = i; } // strict > keeps FIRST max (min idx tie-break)
        }
        s_arg[threadIdx.x] = arg;
        x_seen[g] = (end > start) ? 1.0f : 0.0f;
    }
    __syncthreads();

    // ---- Phase B: gather selected rows, 32 lanes x float4 per row ----
    const int lane = threadIdx.x & 31;
    const int warp = threadIdx.x >> 5;           // 0..7
    #pragma unroll 4
    for (int k = 0; k < GROUPS_PER_BLOCK / 8; ++k) {
        const int gl = warp + k * 8;             // local group 0..255
        const int gg = g0 + gl;
        if (gg >= n_groups) continue;            // tail block only
        const int a = s_arg[gl];                 // warp-uniform
        f4 v = (f4){0.f, 0.f, 0.f, 0.f};
        if (a < n_items) {
            const f4* src = (const f4*)(x_mod + (size_t)a * D_DIM);
            v = __builtin_nontemporal_load(src + lane);
        }
        f4* dst = (f4*)(x_pool + (size_t)gg * D_DIM);
        __builtin_nontemporal_store(v, dst + lane);
    }
}

extern "C" void kernel_launch(void* const* d_in, const int* in_sizes, int n_in,
                              void* d_out, int out_size, void* d_ws, size_t ws_size,
                              hipStream_t stream) {
    // Inputs in setup_inputs() order:
    //   d_in[0] = x_main (G*D fp32)  -- UNUSED by the reference
    //   d_in[1] = x_mod  (N*D fp32)
    //   d_in[2] = x_map  (N*F fp32)
    //   d_in[3] = csr_idx (G+1 int32)
    const float* x_mod   = (const float*)d_in[1];
    const float* x_map   = (const float*)d_in[2];
    const int*   csr_idx = (const int*)d_in[3];

    const int n_items  = in_sizes[1] / D_DIM;       // N = 2000000
    const int n_groups = in_sizes[3] - 1;           // G = 500000

    float* x_pool = (float*)d_out;                            // G*D floats
    float* x_seen = (float*)d_out + (size_t)n_groups * D_DIM; // G floats (0.0/1.0)

    const int grid = (n_groups + GROUPS_PER_BLOCK - 1) / GROUPS_PER_BLOCK; // 1954
    fused_csr_pool_kernel<<<grid, BLOCK_THREADS, 0, stream>>>(
        x_mod, x_map, csr_idx, x_pool, x_seen, n_groups, n_items);
}